// Round 5
// baseline (7049.364 us; speedup 1.0000x reference)
//
#include <hip/hip_runtime.h>
#include <hip/hip_bf16.h>
#include <cstdint>

#define BATCH 4096
#define DIM   512
#define HID   1024
#define TSTEPS 20
#define NBLK  128
#define NTHR  512

typedef unsigned short u16;
typedef short s16x8 __attribute__((ext_vector_type(8)));
typedef float f32x4 __attribute__((ext_vector_type(4)));

__device__ __forceinline__ u16 f2bf(float f) {
    unsigned int u = __float_as_uint(f);
    u = (u + 0x7FFFu + ((u >> 16) & 1u)) >> 16;   // RNE
    return (u16)u;
}

__device__ __forceinline__ float fast_tanh(float x) {
    float ax = __builtin_fabsf(x);
    float e  = __expf(2.0f * ax);                 // inf for large ax -> t = 1
    float t  = 1.0f - 2.0f * __builtin_amdgcn_rcpf(e + 1.0f);
    return __builtin_copysignf(t, x);
}

// Wt[n*K + k] = bf16(W[k*N + n])   (W is [K][N] row-major)
__global__ void transpose_convert(const float* __restrict__ W, u16* __restrict__ Wt,
                                  int K, int N) {
    int n = blockIdx.x * 32 + threadIdx.x;
    int k = blockIdx.y * 8  + threadIdx.y;
    if (n < N && k < K) Wt[(size_t)n * K + k] = f2bf(W[(size_t)k * N + n]);
}

// Frag-tile LDS layout: each (16-row x 32-k) MFMA fragment tile contiguous (1KB).
// elem (r, k) at u16 idx ((k>>3)&3)*128 + r*8 + (k&7).
// A-frag read = ds_read_b128 at tile*1024B + (lane>>4)*256 + (lane&15)*16 -> conflict-free.

__global__ __launch_bounds__(NTHR) void ode_nocomm(
    const float* __restrict__ x0, const float* __restrict__ tgrid,
    const float* __restrict__ b1, const float* __restrict__ b2,
    const u16* __restrict__ W1T,   // [HID][DIM]  bf16
    const u16* __restrict__ W2T,   // [DIM][HID]  bf16
    float* __restrict__ out)
{
    __shared__ u16 hs[64 * 512];   // 64 KiB: h strip [32 rows][1024 hid] as 64 frag-tiles
    __shared__ u16 ys[32 * 512];   // 32 KiB: y strip [32 rows][512 d]    as 32 frag-tiles

    const int tid  = threadIdx.x;
    const int lane = tid & 63;
    const int w    = tid >> 6;            // wave 0..7
    const int row0 = blockIdx.x * 32;     // block's private 32-row strip
    const int lr   = (lane >> 4) * 4;
    const int lc   = lane & 15;
    const int q    = lane >> 4;

    // ---- RK4 state in registers: thread owns (m,cf,j) -> rows m*16+lr+j, col w*64+cf*16+lc ----
    float ybase[2][4][4];
    float kacc[2][4][4];

#pragma unroll
    for (int m = 0; m < 2; ++m)
#pragma unroll
        for (int cf = 0; cf < 4; ++cf)
#pragma unroll
            for (int j = 0; j < 4; ++j) {
                int row = row0 + m * 16 + lr + j;
                int col = w * 64 + cf * 16 + lc;
                float v = x0[(size_t)row * DIM + col];
                ybase[m][cf][j] = v;
                out[(size_t)row * DIM + col] = v;
                ys[((w * 2 + (cf >> 1)) * 2 + m) * 512 +
                   ((cf & 1) * 2 + (lc >> 3)) * 128 + (lr + j) * 8 + (lc & 7)] = f2bf(v);
            }

    // hoisted biases
    float bv1[8], bv2[4];
#pragma unroll
    for (int cg = 0; cg < 8; ++cg) bv1[cg] = b1[w * 128 + cg * 16 + lc];
#pragma unroll
    for (int cf = 0; cf < 4; ++cf) bv2[cf] = b2[w * 64 + cf * 16 + lc];

    // per-lane weight base pointers (B-frag: lane&15 = col, lane>>4 = k-quad)
    const u16* w1lane = W1T + (size_t)(w * 128 + lc) * DIM + q * 8;   // + cg*16*512 + ks*32
    const u16* w2lane = W2T + (size_t)(w * 64  + lc) * HID + q * 8;   // + cf*16*1024 + ks*32

    __syncthreads();

#pragma clang loop unroll(disable)
    for (int ev = 0; ev < 4 * (TSTEPS - 1); ++ev) {
        const int s  = ev >> 2;
        const int st = ev & 3;

        // ========== phase 1: h = tanh(y @ W1 + b1) -> hs   (wave: 32r x 128c, K=512) ==========
        {
            f32x4 acc1[2][8];
#pragma unroll
            for (int m = 0; m < 2; ++m)
#pragma unroll
                for (int cg = 0; cg < 8; ++cg)
                    acc1[m][cg] = (f32x4){0.f, 0.f, 0.f, 0.f};

            s16x8 bA[8], bB[8];
#pragma unroll
            for (int cg = 0; cg < 8; ++cg)
                bA[cg] = *(const s16x8*)(w1lane + cg * 16 * DIM);

#pragma unroll
            for (int ks = 0; ks < 16; ++ks) {
                s16x8* bc = (ks & 1) ? bB : bA;
                s16x8* bn = (ks & 1) ? bA : bB;
                if (ks < 15) {
#pragma unroll
                    for (int cg = 0; cg < 8; ++cg)
                        bn[cg] = *(const s16x8*)(w1lane + cg * 16 * DIM + (ks + 1) * 32);
                }
                s16x8 a0 = *(const s16x8*)&ys[(ks * 2 + 0) * 512 + q * 128 + lc * 8];
                s16x8 a1 = *(const s16x8*)&ys[(ks * 2 + 1) * 512 + q * 128 + lc * 8];
#pragma unroll
                for (int cg = 0; cg < 8; ++cg) {
                    acc1[0][cg] = __builtin_amdgcn_mfma_f32_16x16x32_bf16(a0, bc[cg], acc1[0][cg], 0, 0, 0);
                    acc1[1][cg] = __builtin_amdgcn_mfma_f32_16x16x32_bf16(a1, bc[cg], acc1[1][cg], 0, 0, 0);
                }
            }

            // epilogue: tanh -> hs frag-tiles
#pragma unroll
            for (int m = 0; m < 2; ++m)
#pragma unroll
                for (int cg = 0; cg < 8; ++cg) {
                    int tile = (w * 4 + (cg >> 1)) * 2 + m;
                    int base = tile * 512 + ((cg & 1) * 2 + (lc >> 3)) * 128 + (lc & 7);
#pragma unroll
                    for (int j = 0; j < 4; ++j)
                        hs[base + (lr + j) * 8] = f2bf(fast_tanh(acc1[m][cg][j] + bv1[cg]));
                }
        }
        __syncthreads();

        // ========== phase 2: k = h @ W2 + b2 ; RK4 in regs   (wave: 32r x 64c, K=1024) ==========
        {
            f32x4 acc2[2][4];
#pragma unroll
            for (int m = 0; m < 2; ++m)
#pragma unroll
                for (int cf = 0; cf < 4; ++cf)
                    acc2[m][cf] = (f32x4){0.f, 0.f, 0.f, 0.f};

            s16x8 cA[4], cB[4];
#pragma unroll
            for (int cf = 0; cf < 4; ++cf)
                cA[cf] = *(const s16x8*)(w2lane + cf * 16 * HID);

#pragma unroll
            for (int ks = 0; ks < 32; ++ks) {
                s16x8* bc = (ks & 1) ? cB : cA;
                s16x8* bn = (ks & 1) ? cA : cB;
                if (ks < 31) {
#pragma unroll
                    for (int cf = 0; cf < 4; ++cf)
                        bn[cf] = *(const s16x8*)(w2lane + cf * 16 * HID + (ks + 1) * 32);
                }
                s16x8 a0 = *(const s16x8*)&hs[(ks * 2 + 0) * 512 + q * 128 + lc * 8];
                s16x8 a1 = *(const s16x8*)&hs[(ks * 2 + 1) * 512 + q * 128 + lc * 8];
#pragma unroll
                for (int cf = 0; cf < 4; ++cf) {
                    acc2[0][cf] = __builtin_amdgcn_mfma_f32_16x16x32_bf16(a0, bc[cf], acc2[0][cf], 0, 0, 0);
                    acc2[1][cf] = __builtin_amdgcn_mfma_f32_16x16x32_bf16(a1, bc[cf], acc2[1][cf], 0, 0, 0);
                }
            }

            const float dtv = tgrid[s + 1] - tgrid[s];
            float* yn = out + (size_t)(s + 1) * BATCH * DIM;
#pragma unroll
            for (int m = 0; m < 2; ++m)
#pragma unroll
                for (int cf = 0; cf < 4; ++cf) {
                    int ytile = (w * 2 + (cf >> 1)) * 2 + m;
                    int ybase_i = ytile * 512 + ((cf & 1) * 2 + (lc >> 3)) * 128 + (lc & 7);
#pragma unroll
                    for (int j = 0; j < 4; ++j) {
                        float v = acc2[m][cf][j] + bv2[cf];
                        float yb = ybase[m][cf][j];
                        float ywr;
                        if (st == 0) {
                            kacc[m][cf][j] = v;
                            ywr = yb + 0.5f * dtv * v;
                        } else if (st == 1) {
                            kacc[m][cf][j] += 2.0f * v;
                            ywr = yb + 0.5f * dtv * v;
                        } else if (st == 2) {
                            kacc[m][cf][j] += 2.0f * v;
                            ywr = yb + dtv * v;
                        } else {
                            float y1 = yb + (dtv * (1.0f / 6.0f)) * (kacc[m][cf][j] + v);
                            int row = row0 + m * 16 + lr + j;
                            int col = w * 64 + cf * 16 + lc;
                            yn[(size_t)row * DIM + col] = y1;
                            ybase[m][cf][j] = y1;
                            ywr = y1;
                        }
                        ys[ybase_i + (lr + j) * 8] = f2bf(ywr);
                    }
                }
        }
        __syncthreads();
    }
}

extern "C" void kernel_launch(void* const* d_in, const int* in_sizes, int n_in,
                              void* d_out, int out_size, void* d_ws, size_t ws_size,
                              hipStream_t stream) {
    (void)in_sizes; (void)n_in; (void)out_size; (void)ws_size;
    const float* x0 = (const float*)d_in[0];
    const float* t  = (const float*)d_in[1];
    const float* W1 = (const float*)d_in[2];
    const float* b1 = (const float*)d_in[3];
    const float* W2 = (const float*)d_in[4];
    const float* b2 = (const float*)d_in[5];
    float* out = (float*)d_out;

    char* ws = (char*)d_ws;
    u16* W1T = (u16*)(ws);              // 1 MB [1024][512] bf16
    u16* W2T = (u16*)(ws + (1u << 20)); // 1 MB [512][1024] bf16

    transpose_convert<<<dim3(HID / 32, DIM / 8), dim3(32, 8), 0, stream>>>(W1, W1T, DIM, HID);
    transpose_convert<<<dim3(DIM / 32, HID / 8), dim3(32, 8), 0, stream>>>(W2, W2T, HID, DIM);

    ode_nocomm<<<NBLK, NTHR, 0, stream>>>(x0, t, b1, b2, W1T, W2T, out);
}